// Round 1
// baseline (567.038 us; speedup 1.0000x reference)
//
#include <hip/hip_runtime.h>

namespace {
constexpr int NUM_OBJ_CLS = 151;
constexpr int NUM_REL_CLS = 51;
constexpr int N_OBJ       = 16384;
constexpr int N_PAIRS     = 2000000;

constexpr unsigned OBJ_ELEMS = (unsigned)N_OBJ * NUM_OBJ_CLS;      // 2,473,984
constexpr unsigned OBJ_VEC4  = OBJ_ELEMS / 4u;                     // 618,496 (exact)
constexpr unsigned REL_ELEMS = (unsigned)N_PAIRS * NUM_REL_CLS;    // 102,000,000
constexpr unsigned REL_VEC4  = REL_ELEMS / 4u;                     // 25,500,000 (exact)
}

// obj_dists: softmax(+-1000 onehot) == exact one-hot {1.0, 0.0}.
// Flat float4 writes; per-element row = idx/151, col = idx%151.
__global__ __launch_bounds__(256) void obj_dists_kernel(
        const int* __restrict__ labels, float* __restrict__ out) {
    unsigned e4 = blockIdx.x * blockDim.x + threadIdx.x;
    if (e4 >= OBJ_VEC4) return;
    unsigned e = e4 * 4u;
    float4 v;
    float* vp = reinterpret_cast<float*>(&v);
#pragma unroll
    for (int k = 0; k < 4; ++k) {
        unsigned idx = e + (unsigned)k;
        unsigned i = idx / (unsigned)NUM_OBJ_CLS;        // compiler magic-mul
        unsigned c = idx - i * (unsigned)NUM_OBJ_CLS;
        vp[k] = ((int)c == labels[i]) ? 1.0f : 0.0f;
    }
    reinterpret_cast<float4*>(out)[e4] = v;
}

// rel_dists: out[p*51 + j] = table[(labels[pairs[2p]]*151 + labels[pairs[2p+1]])*51 + j]
// Flattened: each thread produces one aligned float4 of the 102M-float output.
__global__ __launch_bounds__(256) void rel_dists_kernel(
        const int* __restrict__ labels, const int* __restrict__ pairs,
        const float* __restrict__ table, float* __restrict__ out) {
    unsigned stride = gridDim.x * blockDim.x;
    for (unsigned e4 = blockIdx.x * blockDim.x + threadIdx.x; e4 < REL_VEC4;
         e4 += stride) {
        unsigned e = e4 * 4u;
        unsigned p = e / (unsigned)NUM_REL_CLS;          // compiler magic-mul
        unsigned j = e - p * (unsigned)NUM_REL_CLS;
        float4 v;
        float* vp = reinterpret_cast<float*>(&v);
        if (j <= (unsigned)(NUM_REL_CLS - 4)) {
            // fast path (48/51 of units): all 4 elems in one pair's table row
            int h = labels[pairs[2u * p]];
            int t = labels[pairs[2u * p + 1u]];
            const float* row =
                table + (unsigned)(h * NUM_OBJ_CLS + t) * (unsigned)NUM_REL_CLS + j;
            vp[0] = row[0];
            vp[1] = row[1];
            vp[2] = row[2];
            vp[3] = row[3];
        } else {
            // straddles two pairs: per-element gather
#pragma unroll
            for (int k = 0; k < 4; ++k) {
                unsigned idx = e + (unsigned)k;
                unsigned pp = idx / (unsigned)NUM_REL_CLS;
                unsigned jj = idx - pp * (unsigned)NUM_REL_CLS;
                int h = labels[pairs[2u * pp]];
                int t = labels[pairs[2u * pp + 1u]];
                vp[k] = table[(unsigned)(h * NUM_OBJ_CLS + t) * (unsigned)NUM_REL_CLS
                              + jj];
            }
        }
        reinterpret_cast<float4*>(out)[e4] = v;
    }
}

extern "C" void kernel_launch(void* const* d_in, const int* in_sizes, int n_in,
                              void* d_out, int out_size, void* d_ws, size_t ws_size,
                              hipStream_t stream) {
    const int*   labels = (const int*)d_in[0];
    const int*   pairs  = (const int*)d_in[1];
    const float* table  = (const float*)d_in[2];
    float*       out    = (float*)d_out;

    // Output layout: obj_dists (2,473,984 f32) then rel_dists (102,000,000 f32).
    obj_dists_kernel<<<(OBJ_VEC4 + 255u) / 256u, 256, 0, stream>>>(labels, out);
    rel_dists_kernel<<<2048, 256, 0, stream>>>(labels, pairs, table,
                                               out + OBJ_ELEMS);
}

// Round 2
// 482.129 us; speedup vs baseline: 1.1761x; 1.1761x over previous
//
#include <hip/hip_runtime.h>

namespace {
constexpr int NUM_OBJ_CLS = 151;
constexpr int NUM_REL_CLS = 51;
constexpr int N_OBJ       = 16384;
constexpr int N_PAIRS     = 2000000;

constexpr unsigned OBJ_ELEMS = (unsigned)N_OBJ * NUM_OBJ_CLS;      // 2,473,984
constexpr unsigned OBJ_VEC4  = OBJ_ELEMS / 4u;                     // 618,496 (exact)
constexpr unsigned REL_ELEMS = (unsigned)N_PAIRS * NUM_REL_CLS;    // 102,000,000
constexpr unsigned REL_VEC4  = REL_ELEMS / 4u;                     // 25,500,000 (exact)
constexpr unsigned UNROLL      = 4;
constexpr unsigned REL_THREADS = REL_VEC4 / UNROLL;                // 6,375,000 (exact)
constexpr unsigned PAIRS_PER_T = 4;
constexpr unsigned OFF_THREADS = N_PAIRS / PAIRS_PER_T;            // 500,000 (exact)
}

// obj_dists: softmax(+-1000 onehot) == exact one-hot {1.0, 0.0}.
__global__ __launch_bounds__(256) void obj_dists_kernel(
        const int* __restrict__ labels, float* __restrict__ out) {
    unsigned e4 = blockIdx.x * blockDim.x + threadIdx.x;
    if (e4 >= OBJ_VEC4) return;
    unsigned e = e4 * 4u;
    float4 v;
    float* vp = reinterpret_cast<float*>(&v);
#pragma unroll
    for (int k = 0; k < 4; ++k) {
        unsigned idx = e + (unsigned)k;
        unsigned i = idx / (unsigned)NUM_OBJ_CLS;        // compiler magic-mul
        unsigned c = idx - i * (unsigned)NUM_OBJ_CLS;
        vp[k] = ((int)c == labels[i]) ? 1.0f : 0.0f;
    }
    reinterpret_cast<float4*>(out)[e4] = v;
}

// offs[p] = (labels[pairs[2p]]*151 + labels[pairs[2p+1]]) * 51
// 4 pairs/thread: two int4 loads of pairs, one uint4 store.
__global__ __launch_bounds__(256) void pair_offset_kernel(
        const int* __restrict__ labels, const int* __restrict__ pairs,
        unsigned* __restrict__ offs) {
    unsigned t = blockIdx.x * blockDim.x + threadIdx.x;
    if (t >= OFF_THREADS) return;
    int4 a = reinterpret_cast<const int4*>(pairs)[2u * t];
    int4 b = reinterpret_cast<const int4*>(pairs)[2u * t + 1u];
    uint4 o;
    o.x = (unsigned)(labels[a.x] * NUM_OBJ_CLS + labels[a.y]) * (unsigned)NUM_REL_CLS;
    o.y = (unsigned)(labels[a.z] * NUM_OBJ_CLS + labels[a.w]) * (unsigned)NUM_REL_CLS;
    o.z = (unsigned)(labels[b.x] * NUM_OBJ_CLS + labels[b.y]) * (unsigned)NUM_REL_CLS;
    o.w = (unsigned)(labels[b.z] * NUM_OBJ_CLS + labels[b.w]) * (unsigned)NUM_REL_CLS;
    reinterpret_cast<uint4*>(offs)[t] = o;
}

// rel_dists: each thread emits UNROLL independent float4 units (stride = nthreads)
// so 4 offs-loads then 4 table-gathers are in flight simultaneously.
__global__ __launch_bounds__(256) void rel_dists_kernel(
        const unsigned* __restrict__ offs, const float* __restrict__ table,
        float* __restrict__ out) {
    unsigned t = blockIdx.x * blockDim.x + threadIdx.x;
    if (t >= REL_THREADS) return;

    unsigned e4[UNROLL], p[UNROLL], j[UNROLL], b0[UNROLL];
#pragma unroll
    for (unsigned k = 0; k < UNROLL; ++k) {
        e4[k] = t + k * REL_THREADS;
        unsigned e = e4[k] * 4u;
        p[k] = e / (unsigned)NUM_REL_CLS;                // compiler magic-mul
        j[k] = e - p[k] * (unsigned)NUM_REL_CLS;
    }
#pragma unroll
    for (unsigned k = 0; k < UNROLL; ++k) b0[k] = offs[p[k]];   // 4 loads in flight

#pragma unroll
    for (unsigned k = 0; k < UNROLL; ++k) {
        float4 v;
        float* vp = reinterpret_cast<float*>(&v);
        if (j[k] <= (unsigned)(NUM_REL_CLS - 4)) {
            const float* row = table + b0[k] + j[k];
            vp[0] = row[0];
            vp[1] = row[1];
            vp[2] = row[2];
            vp[3] = row[3];
        } else {
            // unit straddles pairs p and p+1 (j in {48,49,50}); p+1 always valid here
            unsigned b1 = offs[p[k] + 1u];
            int from_p = NUM_REL_CLS - (int)j[k];        // 3,2,1
#pragma unroll
            for (int q = 0; q < 4; ++q)
                vp[q] = (q < from_p) ? table[b0[k] + j[k] + (unsigned)q]
                                     : table[b1 + (unsigned)(q - from_p)];
        }
        reinterpret_cast<float4*>(out)[e4[k]] = v;
    }
}

extern "C" void kernel_launch(void* const* d_in, const int* in_sizes, int n_in,
                              void* d_out, int out_size, void* d_ws, size_t ws_size,
                              hipStream_t stream) {
    const int*   labels = (const int*)d_in[0];
    const int*   pairs  = (const int*)d_in[1];
    const float* table  = (const float*)d_in[2];
    float*       out    = (float*)d_out;
    unsigned*    offs   = (unsigned*)d_ws;               // 2M u32 = 8 MB scratch

    obj_dists_kernel<<<(OBJ_VEC4 + 255u) / 256u, 256, 0, stream>>>(labels, out);
    pair_offset_kernel<<<(OFF_THREADS + 255u) / 256u, 256, 0, stream>>>(labels, pairs,
                                                                        offs);
    rel_dists_kernel<<<(REL_THREADS + 255u) / 256u, 256, 0, stream>>>(
        offs, table, out + OBJ_ELEMS);
}

// Round 5
// 461.433 us; speedup vs baseline: 1.2289x; 1.0449x over previous
//
#include <hip/hip_runtime.h>

namespace {
constexpr int NUM_OBJ_CLS = 151;
constexpr int NUM_REL_CLS = 51;
constexpr int N_OBJ       = 16384;
constexpr int N_PAIRS     = 2000000;

constexpr unsigned OBJ_ELEMS = (unsigned)N_OBJ * NUM_OBJ_CLS;      // 2,473,984
constexpr unsigned OBJ_VEC4  = OBJ_ELEMS / 4u;                     // 618,496 (exact)
constexpr unsigned REL_ELEMS = (unsigned)N_PAIRS * NUM_REL_CLS;    // 102,000,000
constexpr unsigned REL_VEC4  = REL_ELEMS / 4u;                     // 25,500,000 (exact)
constexpr unsigned UNROLL      = 4;
constexpr unsigned REL_THREADS = REL_VEC4 / UNROLL;                // 6,375,000 (exact)
constexpr unsigned PAIRS_PER_T = 4;
constexpr unsigned OFF_THREADS = N_PAIRS / PAIRS_PER_T;            // 500,000 (exact)

// clang vector type: __builtin_nontemporal_store requires a real vector type,
// not HIP's float4 class.
typedef float f32x4 __attribute__((ext_vector_type(4)));
}

// obj_dists: softmax(+-1000 onehot) == exact one-hot {1.0, 0.0}.
// Nontemporal stores: write-once output, keep it out of L2.
__global__ __launch_bounds__(256) void obj_dists_kernel(
        const int* __restrict__ labels, float* __restrict__ out) {
    unsigned e4 = blockIdx.x * blockDim.x + threadIdx.x;
    if (e4 >= OBJ_VEC4) return;
    unsigned e = e4 * 4u;
    f32x4 v;
#pragma unroll
    for (int k = 0; k < 4; ++k) {
        unsigned idx = e + (unsigned)k;
        unsigned i = idx / (unsigned)NUM_OBJ_CLS;        // compiler magic-mul
        unsigned c = idx - i * (unsigned)NUM_OBJ_CLS;
        v[k] = ((int)c == labels[i]) ? 1.0f : 0.0f;
    }
    __builtin_nontemporal_store(v, reinterpret_cast<f32x4*>(out) + e4);
}

// offs[p] = (labels[pairs[2p]]*151 + labels[pairs[2p+1]]) * 51
__global__ __launch_bounds__(256) void pair_offset_kernel(
        const int* __restrict__ labels, const int* __restrict__ pairs,
        unsigned* __restrict__ offs) {
    unsigned t = blockIdx.x * blockDim.x + threadIdx.x;
    if (t >= OFF_THREADS) return;
    int4 a = reinterpret_cast<const int4*>(pairs)[2u * t];
    int4 b = reinterpret_cast<const int4*>(pairs)[2u * t + 1u];
    uint4 o;
    o.x = (unsigned)(labels[a.x] * NUM_OBJ_CLS + labels[a.y]) * (unsigned)NUM_REL_CLS;
    o.y = (unsigned)(labels[a.z] * NUM_OBJ_CLS + labels[a.w]) * (unsigned)NUM_REL_CLS;
    o.z = (unsigned)(labels[b.x] * NUM_OBJ_CLS + labels[b.y]) * (unsigned)NUM_REL_CLS;
    o.w = (unsigned)(labels[b.z] * NUM_OBJ_CLS + labels[b.w]) * (unsigned)NUM_REL_CLS;
    reinterpret_cast<uint4*>(offs)[t] = o;
}

// rel_dists: branchless. Each thread emits UNROLL independent float4 units.
// Per unit: load offs[p] and offs[p+1] unconditionally, per-element cndmask
// selects (b0 + jj) vs (b1 + jj-51). No divergence, chain depth 2, 7 VMEM/unit.
// NOTE: offs[p+1] can read offs[N_PAIRS] (one word past the 8 MB offs array)
// for the final units; ws_size >> 8 MB so the load is safe, and its value is
// never selected (jj<51 always holds when p is the last pair).
__global__ __launch_bounds__(256) void rel_dists_kernel(
        const unsigned* __restrict__ offs, const float* __restrict__ table,
        float* __restrict__ out) {
    unsigned t = blockIdx.x * blockDim.x + threadIdx.x;
    if (t >= REL_THREADS) return;

    unsigned e4[UNROLL], j0[UNROLL], b0[UNROLL], b1[UNROLL];
#pragma unroll
    for (unsigned k = 0; k < UNROLL; ++k) {
        e4[k] = t + k * REL_THREADS;
        unsigned e = e4[k] * 4u;
        unsigned p = e / (unsigned)NUM_REL_CLS;          // compiler magic-mul
        j0[k] = e - p * (unsigned)NUM_REL_CLS;
        b0[k] = offs[p];                                  // both bases in flight
        b1[k] = offs[p + 1u];
    }

#pragma unroll
    for (unsigned k = 0; k < UNROLL; ++k) {
        f32x4 v;
#pragma unroll
        for (int q = 0; q < 4; ++q) {
            unsigned jj = j0[k] + (unsigned)q;
            unsigned idx = (jj < (unsigned)NUM_REL_CLS)
                               ? (b0[k] + jj)
                               : (b1[k] + jj - (unsigned)NUM_REL_CLS);
            v[q] = table[idx];
        }
        __builtin_nontemporal_store(v, reinterpret_cast<f32x4*>(out) + e4[k]);
    }
}

extern "C" void kernel_launch(void* const* d_in, const int* in_sizes, int n_in,
                              void* d_out, int out_size, void* d_ws, size_t ws_size,
                              hipStream_t stream) {
    const int*   labels = (const int*)d_in[0];
    const int*   pairs  = (const int*)d_in[1];
    const float* table  = (const float*)d_in[2];
    float*       out    = (float*)d_out;
    unsigned*    offs   = (unsigned*)d_ws;               // 2M u32 = 8 MB scratch

    obj_dists_kernel<<<(OBJ_VEC4 + 255u) / 256u, 256, 0, stream>>>(labels, out);
    pair_offset_kernel<<<(OFF_THREADS + 255u) / 256u, 256, 0, stream>>>(labels, pairs,
                                                                        offs);
    rel_dists_kernel<<<(REL_THREADS + 255u) / 256u, 256, 0, stream>>>(
        offs, table, out + OBJ_ELEMS);
}

// Round 6
// 447.012 us; speedup vs baseline: 1.2685x; 1.0323x over previous
//
#include <hip/hip_runtime.h>

namespace {
constexpr int NUM_OBJ_CLS = 151;
constexpr int NUM_REL_CLS = 51;
constexpr int N_OBJ       = 16384;
constexpr int N_PAIRS     = 2000000;

constexpr unsigned OBJ_ELEMS = (unsigned)N_OBJ * NUM_OBJ_CLS;      // 2,473,984
constexpr unsigned OBJ_VEC4  = OBJ_ELEMS / 4u;                     // 618,496 (exact)
constexpr unsigned REL_ELEMS = (unsigned)N_PAIRS * NUM_REL_CLS;    // 102,000,000
constexpr unsigned REL_VEC4  = REL_ELEMS / 4u;                     // 25,500,000 (exact)
constexpr unsigned UNROLL      = 4;
constexpr unsigned REL_THREADS = REL_VEC4 / UNROLL;                // 6,375,000 (exact)
constexpr unsigned PAIRS_PER_T = 4;
constexpr unsigned OFF_THREADS = N_PAIRS / PAIRS_PER_T;            // 500,000 (exact)

// clang vector type (nontemporal builtin needs a real vector type).
typedef float f32x4 __attribute__((ext_vector_type(4)));
// 4-byte-aligned 16B load wrapper: table rows have 204 B stride, so unit
// sources are only dword-aligned. gfx950 global dwordx4 needs only dword
// alignment; worst case the compiler splits it (no worse than 4 scalars).
struct __attribute__((packed, aligned(4))) f32x4_u { f32x4 v; };
__device__ __forceinline__ f32x4 load4u(const float* p) {
    return reinterpret_cast<const f32x4_u*>(p)->v;
}
}

// obj_dists: softmax(+-1000 onehot) == exact one-hot {1.0, 0.0}.
__global__ __launch_bounds__(256) void obj_dists_kernel(
        const int* __restrict__ labels, float* __restrict__ out) {
    unsigned e4 = blockIdx.x * blockDim.x + threadIdx.x;
    if (e4 >= OBJ_VEC4) return;
    unsigned e = e4 * 4u;
    f32x4 v;
#pragma unroll
    for (int k = 0; k < 4; ++k) {
        unsigned idx = e + (unsigned)k;
        unsigned i = idx / (unsigned)NUM_OBJ_CLS;        // compiler magic-mul
        unsigned c = idx - i * (unsigned)NUM_OBJ_CLS;
        v[k] = ((int)c == labels[i]) ? 1.0f : 0.0f;
    }
    __builtin_nontemporal_store(v, reinterpret_cast<f32x4*>(out) + e4);
}

// offs[p] = (labels[pairs[2p]]*151 + labels[pairs[2p+1]]) * 51
// Thread 0 also writes offs[N_PAIRS] = 0: the rel kernel's tail units
// dereference table + offs[p+1] unconditionally, so it must be a valid offset.
__global__ __launch_bounds__(256) void pair_offset_kernel(
        const int* __restrict__ labels, const int* __restrict__ pairs,
        unsigned* __restrict__ offs) {
    unsigned t = blockIdx.x * blockDim.x + threadIdx.x;
    if (t >= OFF_THREADS) return;
    if (t == 0) offs[N_PAIRS] = 0u;
    int4 a = reinterpret_cast<const int4*>(pairs)[2u * t];
    int4 b = reinterpret_cast<const int4*>(pairs)[2u * t + 1u];
    uint4 o;
    o.x = (unsigned)(labels[a.x] * NUM_OBJ_CLS + labels[a.y]) * (unsigned)NUM_REL_CLS;
    o.y = (unsigned)(labels[a.z] * NUM_OBJ_CLS + labels[a.w]) * (unsigned)NUM_REL_CLS;
    o.z = (unsigned)(labels[b.x] * NUM_OBJ_CLS + labels[b.y]) * (unsigned)NUM_REL_CLS;
    o.w = (unsigned)(labels[b.z] * NUM_OBJ_CLS + labels[b.w]) * (unsigned)NUM_REL_CLS;
    reinterpret_cast<uint4*>(offs)[t] = o;
}

// rel_dists: one unaligned 16B table load per unit (was 4 scalar gathers), plus
// a 16B load at the start of row p+1. Branchless window-select handles the
// 3/51 straddling units: v[q] = window(a,b)[q + s], s = j0 - min(j0,47).
// All vector indices compile-time constant (3 v_cmp + 12 v_cndmask per unit).
__global__ __launch_bounds__(256) void rel_dists_kernel(
        const unsigned* __restrict__ offs, const float* __restrict__ table,
        float* __restrict__ out) {
    unsigned t = blockIdx.x * blockDim.x + threadIdx.x;
    if (t >= REL_THREADS) return;

    unsigned e4[UNROLL], s_[UNROLL], jc[UNROLL], b0[UNROLL], b1[UNROLL];
#pragma unroll
    for (unsigned k = 0; k < UNROLL; ++k) {
        e4[k] = t + k * REL_THREADS;
        unsigned e = e4[k] * 4u;
        unsigned p = e / (unsigned)NUM_REL_CLS;          // compiler magic-mul
        unsigned j0 = e - p * (unsigned)NUM_REL_CLS;
        jc[k] = (j0 < 47u) ? j0 : 47u;
        s_[k] = j0 - jc[k];                              // 0 for 48/51 units
        b0[k] = offs[p];                                 // 2*UNROLL offs loads in flight
        b1[k] = offs[p + 1u];
    }

    f32x4 a[UNROLL], b[UNROLL];
#pragma unroll
    for (unsigned k = 0; k < UNROLL; ++k) {              // 2*UNROLL table loads in flight
        a[k] = load4u(table + b0[k] + jc[k]);
        b[k] = load4u(table + b1[k]);
    }

#pragma unroll
    for (unsigned k = 0; k < UNROLL; ++k) {
        unsigned s = s_[k];
        f32x4 v;
        v.x = (s == 0u) ? a[k].x : (s == 1u) ? a[k].y : (s == 2u) ? a[k].z : a[k].w;
        v.y = (s == 0u) ? a[k].y : (s == 1u) ? a[k].z : (s == 2u) ? a[k].w : b[k].x;
        v.z = (s == 0u) ? a[k].z : (s == 1u) ? a[k].w : (s == 2u) ? b[k].x : b[k].y;
        v.w = (s == 0u) ? a[k].w : (s == 1u) ? b[k].x : (s == 2u) ? b[k].y : b[k].z;
        __builtin_nontemporal_store(v, reinterpret_cast<f32x4*>(out) + e4[k]);
    }
}

extern "C" void kernel_launch(void* const* d_in, const int* in_sizes, int n_in,
                              void* d_out, int out_size, void* d_ws, size_t ws_size,
                              hipStream_t stream) {
    const int*   labels = (const int*)d_in[0];
    const int*   pairs  = (const int*)d_in[1];
    const float* table  = (const float*)d_in[2];
    float*       out    = (float*)d_out;
    unsigned*    offs   = (unsigned*)d_ws;               // 2M+1 u32 scratch

    obj_dists_kernel<<<(OBJ_VEC4 + 255u) / 256u, 256, 0, stream>>>(labels, out);
    pair_offset_kernel<<<(OFF_THREADS + 255u) / 256u, 256, 0, stream>>>(labels, pairs,
                                                                        offs);
    rel_dists_kernel<<<(REL_THREADS + 255u) / 256u, 256, 0, stream>>>(
        offs, table, out + OBJ_ELEMS);
}